// Round 21
// baseline (61.832 us; speedup 1.0000x reference)
//
#include <hip/hip_runtime.h>
#include <hip/hip_bf16.h>

// ContrastiveLoss: loss = ( sum_{same & sim<1} (1-sim) + sum_{diff & sim>0.5} sim ) / n
// sim = E E^T, n=8192, d=512. int8 MFMA (mfma_i32_16x16x64_i8), exact i32
// accumulation, quant scale 24, dequant 1/576.
// R21 = R20 with B REMOVED FROM LDS: b fragments are loaded direct from
// global/L2 into REGISTERS one window ahead (b_cur/b_next double-buffer).
// Waves sharing wcol duplicate B reads from L2 (cheap: 3% HBM util); in
// exchange per thread-window we drop 1 of 2 glls and 2 of 6 ds_reads ->
// LDS pipe (the dominant cost, ~20us) drops ~35%. LDS = A-only ring-3 (24KB).
// vmcnt accounting (order-pinned): window issue = [a ds_reads + b(p+1)x2] |
// gllA(p+2). At window p wait, outstanding = b(p)x2, gllA(p+1) -> vmcnt(1)
// steady ("all but newest 1 done" = A(p) landed + b(p) in regs), vmcnt(0)
// last. Prologue: b(0)x2 then gllA(0),gllA(1) -> same invariant at p=0.
// __launch_bounds__(512,4) pins regs <=128 (occupancy guard for +16 VGPR).
// A swizzle (row>>1)&3 both-sides, T1, triangular grid, epilogue: as R20.

typedef int i32x4 __attribute__((ext_vector_type(4)));

#define N_EMB 8192
#define D_EMB 512
#define BM    128
#define HKB   64                 // K-bytes per window
#define NPH   (D_EMB / HKB)      // 8 windows
#define TILES (N_EMB / BM)       // 64
#define NBLK  (TILES * (TILES + 1) / 2)   // 2080
#define MARGIN_F 0.5f
#define QSCALE 24.0f
#define DEQ    (1.0f / (QSCALE * QSCALE))  // 1/576
#define HBYT  (BM * HKB)         // 8192 B A half-buffer

__device__ __forceinline__ void gll16(const void* g, void* l) {
    __builtin_amdgcn_global_load_lds(
        (const __attribute__((address_space(1))) void*)g,
        (__attribute__((address_space(3))) void*)l,
        16 /*bytes*/, 0 /*offset*/, 0 /*aux*/);
}

// fp32 -> int8 (scale 24, clamp +-127). 16 floats -> 16 bytes per thread.
__global__ __launch_bounds__(256) void quant_kernel(const float* __restrict__ in,
                                                    int4* __restrict__ out, int n16) {
    int i = blockIdx.x * blockDim.x + threadIdx.x;
    if (i >= n16) return;
    const float4* p = reinterpret_cast<const float4*>(in) + i * 4;
    int4 o;
    int* po = reinterpret_cast<int*>(&o);
#pragma unroll
    for (int j = 0; j < 4; ++j) {
        float4 v = p[j];
        int b0 = (int)rintf(fminf(fmaxf(v.x * QSCALE, -127.f), 127.f));
        int b1 = (int)rintf(fminf(fmaxf(v.y * QSCALE, -127.f), 127.f));
        int b2 = (int)rintf(fminf(fmaxf(v.z * QSCALE, -127.f), 127.f));
        int b3 = (int)rintf(fminf(fmaxf(v.w * QSCALE, -127.f), 127.f));
        po[j] = (b0 & 255) | ((b1 & 255) << 8) | ((b2 & 255) << 16) | ((b3 & 255) << 24);
    }
    out[i] = o;
}

__global__ __launch_bounds__(512, 4) void loss_kernel(const char* __restrict__ E8,
                                                      const int* __restrict__ label,
                                                      float* __restrict__ partials) {
    // T1: XCD-contiguous logical tile index (2080 % 8 == 0)
    const int bid = blockIdx.x;
    const int t = (bid & 7) * (NBLK / 8) + (bid >> 3);

    // triangular decode: t -> (tr, tc), tr <= tc (validated R2..R20)
    int tr = (int)(64.5f - sqrtf(4160.25f - 2.0f * (float)t));
    while ((tr + 1) * TILES - ((tr + 1) * tr) / 2 <= t) ++tr;
    while (tr * TILES - (tr * (tr - 1)) / 2 > t) --tr;
    const int tc = tr + (t - (tr * TILES - (tr * (tr - 1)) / 2));

    __shared__ char  lds[3][HBYT];   // A-only ring-3 = 24 KB
    __shared__ float red[8];

    const int tid  = threadIdx.x;
    const int wid  = tid >> 6, lane = tid & 63;
    const int wrow = wid >> 2, wcol = wid & 3;   // 2x4 waves, each 64x32 out
    const int fr   = lane & 15;                  // fragment row(A)/row(B)/col(C)
    const int kq   = lane >> 4;                  // k-16B-chunk 0..3
    const int row0 = tr * BM, col0 = tc * BM;

    // A staging: 128 rows x 64 B = 512 x 16B slots; thread covers slot tid.
    // Phys chunk c of row r holds LOGICAL chunk c ^ ((r>>1)&3): inverse
    // swizzle on global source, lane-linear LDS dest. row=tid>>2.
    const int sw = (((tid & 3) ^ ((tid >> 3) & 3)) << 4);
    const int r0 = tid >> 2;
    const char* gA0 = E8 + (size_t)(row0 + r0) * D_EMB + sw;
    const int d0 = tid << 4;

    // B direct-from-L2 fragment base pointers (per-wave private)
    const char* gB[2];
#pragma unroll
    for (int n = 0; n < 2; ++n)
        gB[n] = E8 + (size_t)(col0 + wcol * 32 + n * 16 + fr) * D_EMB + (kq << 4);

    i32x4 acc[4][2] = {};

    // ds_read phys chunk: kq ^ ((row>>1)&3); fragment rows = X*16+fr ->
    // (row>>1)&3 = (fr>>1)&3.
    const int psw = ((kq ^ ((fr >> 1) & 3)) << 4);

    // ---- prologue: b(0) into regs FIRST, then gllA(0), gllA(1) ----
    i32x4 b_cur[2], b_next[2];
#pragma unroll
    for (int n = 0; n < 2; ++n)
        b_cur[n] = *reinterpret_cast<const i32x4*>(gB[n]);
    __builtin_amdgcn_sched_barrier(0);           // pin: b(0) before glls
    gll16(gA0,       &lds[0][d0]);
    gll16(gA0 + HKB, &lds[1][d0]);
    __builtin_amdgcn_sched_barrier(0);

#pragma unroll
    for (int p = 0; p < NPH; ++p) {
        const int rg = p % 3;
        // counted wait: all but newest 1 done = A(p) landed (gll issued p-2)
        // AND b(p) regs ready (loads issued p-1); gllA(p+1) may stay in flight.
        if (p < NPH - 1) {
            asm volatile("s_waitcnt vmcnt(1)" ::: "memory");
        } else {
            asm volatile("s_waitcnt vmcnt(0)" ::: "memory");
        }
        __builtin_amdgcn_s_barrier();        // publish A(p); ring (p+2)%3 free
        __builtin_amdgcn_sched_barrier(0);   // reads must not hoist above barrier

        // critical path: this window's A fragment reads (ordinary ds loads;
        // compiler emits fine-grained counted lgkmcnt before each MFMA use)
        i32x4 a[4];
#pragma unroll
        for (int m = 0; m < 4; ++m)
            a[m] = *reinterpret_cast<const i32x4*>(
                &lds[rg][((wrow * 64 + m * 16 + fr) << 6) + psw]);

        // prefetch b(p+1) into regs (1-window lead hides L2 latency)
        if (p + 1 < NPH) {
#pragma unroll
            for (int n = 0; n < 2; ++n)
                b_next[n] = *reinterpret_cast<const i32x4*>(gB[n] + (p + 1) * HKB);
        }
        __builtin_amdgcn_sched_barrier(0);   // pin: b(p+1) issued BEFORE gllA

        // stage A(p+2) (last readers retired before this window's barrier)
        if (p + 2 < NPH) {
            gll16(gA0 + (p + 2) * HKB, &lds[(p + 2) % 3][d0]);
        }
        __builtin_amdgcn_sched_barrier(0);

        __builtin_amdgcn_s_setprio(1);
#pragma unroll
        for (int m = 0; m < 4; ++m)
#pragma unroll
            for (int n = 0; n < 2; ++n)
                acc[m][n] = __builtin_amdgcn_mfma_i32_16x16x64_i8(a[m], b_cur[n], acc[m][n], 0, 0, 0);
        __builtin_amdgcn_s_setprio(0);

        // rotate b registers (static; full unroll -> SSA, no scratch)
#pragma unroll
        for (int n = 0; n < 2; ++n) b_cur[n] = b_next[n];
    }

    // ---- epilogue: C/D layout col = lane&15, row = (lane>>4)*4 + reg.
    float local = 0.f;
    int lj[2];
#pragma unroll
    for (int n = 0; n < 2; ++n) lj[n] = label[col0 + wcol * 32 + n * 16 + fr];
    const int rb = kq << 2;
#pragma unroll
    for (int m = 0; m < 4; ++m) {
#pragma unroll
        for (int r = 0; r < 4; ++r) {
            const int li = label[row0 + wrow * 64 + m * 16 + rb + r];
#pragma unroll
            for (int n = 0; n < 2; ++n) {
                const float s = (float)acc[m][n][r] * DEQ;
                if (li == lj[n]) {
                    if (s < 1.0f) local += 1.0f - s;
                } else if (s > MARGIN_F) {
                    local += s;
                }
            }
        }
    }
    if (tr != tc) local *= 2.0f;   // off-diag tile stands for (i,j) and (j,i)

#pragma unroll
    for (int off = 32; off > 0; off >>= 1) local += __shfl_xor(local, off);
    if (lane == 0) red[wid] = local;
    __syncthreads();
    if (tid == 0) {
        float s = 0.f;
#pragma unroll
        for (int i = 0; i < 8; ++i) s += red[i];
        partials[t] = s;
    }
}

__global__ __launch_bounds__(256) void reduce_kernel(const float* __restrict__ partials,
                                                     float* __restrict__ out, int nb) {
    float s = 0.f;
    for (int i = threadIdx.x; i < nb; i += 256) s += partials[i];
#pragma unroll
    for (int off = 32; off > 0; off >>= 1) s += __shfl_xor(s, off);
    __shared__ float red[4];
    if ((threadIdx.x & 63) == 0) red[threadIdx.x >> 6] = s;
    __syncthreads();
    if (threadIdx.x == 0) {
        out[0] = (red[0] + red[1] + red[2] + red[3]) * (1.0f / (float)N_EMB);
        out[1] = 0.f;
        out[2] = 0.f;
    }
}

extern "C" void kernel_launch(void* const* d_in, const int* in_sizes, int n_in,
                              void* d_out, int out_size, void* d_ws, size_t ws_size,
                              hipStream_t stream) {
    const float* emb   = (const float*)d_in[0];
    const int*   label = (const int*)d_in[1];
    float*       out   = (float*)d_out;

    char*  E8      = (char*)d_ws;                                   // 4 MB
    float* partial = (float*)((char*)d_ws + (size_t)N_EMB * D_EMB); // 8.3 KB

    const int n16 = N_EMB * D_EMB / 16;
    quant_kernel<<<(n16 + 255) / 256, 256, 0, stream>>>(emb, (int4*)E8, n16);

    loss_kernel<<<NBLK, 512, 0, stream>>>(E8, label, partial);

    reduce_kernel<<<1, 256, 0, stream>>>(partial, out, NBLK);
}

// Round 22
// 45.814 us; speedup vs baseline: 1.3496x; 1.3496x over previous
//
#include <hip/hip_runtime.h>
#include <hip/hip_bf16.h>

// ContrastiveLoss: loss = ( sum_{same & sim<1} (1-sim) + sum_{diff & sim>0.5} sim ) / n
// sim = E E^T, n=8192, d=512. int8 MFMA (mfma_i32_16x16x64_i8), exact i32
// accumulation, quant scale 24, dequant 1/576.
// R22 = R20's proven window interior (ring-3, counted vmcnt, ONE barrier,
// reads-before-stage, unpinned lgkm, (row>>1)&3 swizzle both-sides, T1) on the
// BIG-WAVE-TILE geometry: block 256x128, 8 waves (4x2) of 64x64 each.
// Rationale: LDS reads scale with wave perimeter; 64x64 tiles (perimeter 128,
// area 4096) cut LDS bytes/FLOP 1.5x vs 64x32 (perimeter 96, area 2048) ->
// LDS pipe (dominant, ~13-20us) drops to ~9-11. R12 was this geometry but
// lacked every interior lever (two barriers, lgkm pin, 4-way-conflict swizzle).
// Register control: b scoped per n-step (peak ~110 unified), launch_bounds
// (512,4) pins <=128 so occupancy stays 2 blocks/CU (16 waves).

typedef int i32x4 __attribute__((ext_vector_type(4)));

#define N_EMB 8192
#define D_EMB 512
#define BMR   256                // block rows (A panel)
#define BNC   128                // block cols (B panel)
#define HKB   64                 // K-bytes per window
#define NPH   (D_EMB / HKB)      // 8 windows
#define RT    (N_EMB / BMR)      // 32
#define NBLK  1056               // #{(R,C): 0<=R<32, 2R<=C<64}
#define MARGIN_F 0.5f
#define QSCALE 24.0f
#define DEQ    (1.0f / (QSCALE * QSCALE))  // 1/576
#define ABYT  (BMR * HKB)        // 16384 B A half-buffer
#define BBYT  (BNC * HKB)        // 8192 B B half-buffer

__device__ __forceinline__ void gll16(const void* g, void* l) {
    __builtin_amdgcn_global_load_lds(
        (const __attribute__((address_space(1))) void*)g,
        (__attribute__((address_space(3))) void*)l,
        16 /*bytes*/, 0 /*offset*/, 0 /*aux*/);
}

// fp32 -> int8 (scale 24, clamp +-127). 16 floats -> 16 bytes per thread.
__global__ __launch_bounds__(256) void quant_kernel(const float* __restrict__ in,
                                                    int4* __restrict__ out, int n16) {
    int i = blockIdx.x * blockDim.x + threadIdx.x;
    if (i >= n16) return;
    const float4* p = reinterpret_cast<const float4*>(in) + i * 4;
    int4 o;
    int* po = reinterpret_cast<int*>(&o);
#pragma unroll
    for (int j = 0; j < 4; ++j) {
        float4 v = p[j];
        int b0 = (int)rintf(fminf(fmaxf(v.x * QSCALE, -127.f), 127.f));
        int b1 = (int)rintf(fminf(fmaxf(v.y * QSCALE, -127.f), 127.f));
        int b2 = (int)rintf(fminf(fmaxf(v.z * QSCALE, -127.f), 127.f));
        int b3 = (int)rintf(fminf(fmaxf(v.w * QSCALE, -127.f), 127.f));
        po[j] = (b0 & 255) | ((b1 & 255) << 8) | ((b2 & 255) << 16) | ((b3 & 255) << 24);
    }
    out[i] = o;
}

__global__ __launch_bounds__(512, 4) void loss_kernel(const char* __restrict__ E8,
                                                      const int* __restrict__ label,
                                                      float* __restrict__ partials) {
    // T1: XCD-contiguous logical index (1056 % 8 == 0)
    const int bid = blockIdx.x;
    const int t = (bid & 7) * (NBLK / 8) + (bid >> 3);

    // decode t -> (R, C), C >= 2R (validated R7/R12); rows-before(R) = R*(65-R)
    int R = (int)((65.0f - sqrtf(4225.0f - 4.0f * (float)t)) * 0.5f);
    if (R < 0) R = 0; if (R > RT - 1) R = RT - 1;
    while ((R + 1) * (65 - (R + 1)) <= t) ++R;
    while (R * (65 - R) > t) --R;
    const int C = 2 * R + (t - R * (65 - R));

    __shared__ char  lds[3][ABYT + BBYT];   // ring-3 = 72 KB
    __shared__ float red[8];

    const int tid  = threadIdx.x;
    const int wid  = tid >> 6, lane = tid & 63;
    const int wrow = wid >> 1, wcol = wid & 1;   // 4x2 waves, each 64x64 out
    const int fr   = lane & 15;                  // fragment row(A)/row(B)/col(C)
    const int kq   = lane >> 4;                  // k-16B-chunk 0..3
    const int row0 = R * BMR, col0 = C * BNC;

    // staging: A = 256 rows x 64B = 1024 slots (thread: slots tid, tid+512);
    // B = 128 rows x 64B = 512 slots (thread: slot tid). Phys chunk c of row r
    // holds LOGICAL chunk c ^ ((r>>1)&3); inverse swizzle on global source,
    // lane-linear LDS dest. All three slots share (r>>1)&3 = (tid>>3)&3.
    const int sw = (((tid & 3) ^ ((tid >> 3) & 3)) << 4);
    const int r0 = tid >> 2;
    const char* gA0 = E8 + (size_t)(row0 + r0) * D_EMB + sw;
    const char* gA1 = E8 + (size_t)(row0 + 128 + r0) * D_EMB + sw;
    const char* gB0 = E8 + (size_t)(col0 + r0) * D_EMB + sw;
    const int dA0 = tid << 4;
    const int dA1 = (tid + 512) << 4;
    const int dB  = ABYT + (tid << 4);

    i32x4 acc[4][4] = {};

    // ds_read phys chunk: kq ^ ((row>>1)&3); fragment rows = X*16+fr ->
    // (row>>1)&3 = (fr>>1)&3 (X*16 only touches bits >=4).
    const int psw = ((kq ^ ((fr >> 1) & 3)) << 4);

    // prologue: stage windows 0 and 1 (6 glls outstanding per thread)
    gll16(gA0,       &lds[0][dA0]); gll16(gA1,       &lds[0][dA1]);
    gll16(gB0,       &lds[0][dB]);
    gll16(gA0 + HKB, &lds[1][dA0]); gll16(gA1 + HKB, &lds[1][dA1]);
    gll16(gB0 + HKB, &lds[1][dB]);

#pragma unroll
    for (int p = 0; p < NPH; ++p) {
        const int rg = p % 3;
        // counted wait: all but newest 3 done = window p landed; p+1's 3 fly.
        if (p < NPH - 1) {
            asm volatile("s_waitcnt vmcnt(3)" ::: "memory");
        } else {
            asm volatile("s_waitcnt vmcnt(0)" ::: "memory");
        }
        __builtin_amdgcn_s_barrier();        // publish window p; ring (p+2)%3 free
        __builtin_amdgcn_sched_barrier(0);   // reads must not hoist above barrier

        // critical path: A fragment reads (ordinary loads -> compiler emits
        // fine-grained counted lgkmcnt before each MFMA use)
        i32x4 a[4];
#pragma unroll
        for (int m = 0; m < 4; ++m)
            a[m] = *reinterpret_cast<const i32x4*>(
                &lds[rg][((wrow * 64 + m * 16 + fr) << 6) + psw]);

        // stage window p+2 (last readers retired before this window's barrier)
        if (p + 2 < NPH) {
            const int rg2 = (p + 2) % 3;
            const int ko  = (p + 2) * HKB;
            gll16(gA0 + ko, &lds[rg2][dA0]);
            gll16(gA1 + ko, &lds[rg2][dA1]);
            gll16(gB0 + ko, &lds[rg2][dB]);
        }

        // per-n: one B fragment read + 4 MFMAs (limits b live range to 4 regs)
        __builtin_amdgcn_s_setprio(1);
#pragma unroll
        for (int n = 0; n < 4; ++n) {
            i32x4 b = *reinterpret_cast<const i32x4*>(
                &lds[rg][ABYT + ((wcol * 64 + n * 16 + fr) << 6) + psw]);
#pragma unroll
            for (int m = 0; m < 4; ++m)
                acc[m][n] = __builtin_amdgcn_mfma_i32_16x16x64_i8(a[m], b, acc[m][n], 0, 0, 0);
        }
        __builtin_amdgcn_s_setprio(0);
    }

    // ---- epilogue: C/D layout col = lane&15, row = (lane>>4)*4 + reg.
    // Elementwise weight (gi<gj)?2:0 (R7/R12-validated).
    float local = 0.f;
    int lj[4];
#pragma unroll
    for (int n = 0; n < 4; ++n) lj[n] = label[col0 + wcol * 64 + n * 16 + fr];
    const int rb = kq << 2;
#pragma unroll
    for (int m = 0; m < 4; ++m) {
#pragma unroll
        for (int r = 0; r < 4; ++r) {
            const int gi = row0 + wrow * 64 + m * 16 + rb + r;
            const int li = label[gi];
#pragma unroll
            for (int n = 0; n < 4; ++n) {
                const int gj = col0 + wcol * 64 + n * 16 + fr;
                const float s = (float)acc[m][n][r] * DEQ;
                float term = 0.f;
                if (li == lj[n]) {
                    if (s < 1.0f) term = 1.0f - s;
                } else if (s > MARGIN_F) {
                    term = s;
                }
                local += (gi < gj) ? 2.0f * term : 0.f;
            }
        }
    }

#pragma unroll
    for (int off = 32; off > 0; off >>= 1) local += __shfl_xor(local, off);
    if (lane == 0) red[wid] = local;
    __syncthreads();
    if (tid == 0) {
        float s = 0.f;
#pragma unroll
        for (int i = 0; i < 8; ++i) s += red[i];
        partials[t] = s;
    }
}

__global__ __launch_bounds__(256) void reduce_kernel(const float* __restrict__ partials,
                                                     float* __restrict__ out, int nb) {
    float s = 0.f;
    for (int i = threadIdx.x; i < nb; i += 256) s += partials[i];
#pragma unroll
    for (int off = 32; off > 0; off >>= 1) s += __shfl_xor(s, off);
    __shared__ float red[4];
    if ((threadIdx.x & 63) == 0) red[threadIdx.x >> 6] = s;
    __syncthreads();
    if (threadIdx.x == 0) {
        out[0] = (red[0] + red[1] + red[2] + red[3]) * (1.0f / (float)N_EMB);
        out[1] = 0.f;
        out[2] = 0.f;
    }
}

extern "C" void kernel_launch(void* const* d_in, const int* in_sizes, int n_in,
                              void* d_out, int out_size, void* d_ws, size_t ws_size,
                              hipStream_t stream) {
    const float* emb   = (const float*)d_in[0];
    const int*   label = (const int*)d_in[1];
    float*       out   = (float*)d_out;

    char*  E8      = (char*)d_ws;                                   // 4 MB
    float* partial = (float*)((char*)d_ws + (size_t)N_EMB * D_EMB); // 4.2 KB

    const int n16 = N_EMB * D_EMB / 16;
    quant_kernel<<<(n16 + 255) / 256, 256, 0, stream>>>(emb, (int4*)E8, n16);

    loss_kernel<<<NBLK, 512, 0, stream>>>(E8, label, partial);

    reduce_kernel<<<1, 256, 0, stream>>>(partial, out, NBLK);
}